// Round 2
// baseline (567.199 us; speedup 1.0000x reference)
//
#include <hip/hip_runtime.h>
#include <hip/hip_bf16.h>
#include <stdint.h>

// MoE LoRA: N=16384, D_IN=4096, D_OUT=4096, RANK=64, TOPK=8.
// Dtype self-detection: round-1 NaN showed bf16-reads of (likely) fp32 data.
// A probe kernel inspects raw bits and sets device flags; compute kernels
// branch uniformly on them. Internal math is fp32 either way.
#define NROWS 16384
#define D_IN  4096
#define D_OUT 4096
#define RANK  64
#define TOPK  8

typedef __hip_bfloat16 bf16;

__device__ int g_is_fp32;   // 1 if tensors are fp32, 0 if bf16
__device__ int g_idx64;     // 1 if indices are int64 on device, 0 if int32
__device__ float g_up_t[RANK * D_OUT];   // transposed up_w, fp32 internal (1 MB)

__device__ __forceinline__ void unpack8(uint4 raw, float f[8]) {
    const unsigned u0 = raw.x, u1 = raw.y, u2 = raw.z, u3 = raw.w;
    f[0] = __uint_as_float(u0 << 16);
    f[1] = __uint_as_float(u0 & 0xffff0000u);
    f[2] = __uint_as_float(u1 << 16);
    f[3] = __uint_as_float(u1 & 0xffff0000u);
    f[4] = __uint_as_float(u2 << 16);
    f[5] = __uint_as_float(u2 & 0xffff0000u);
    f[6] = __uint_as_float(u3 << 16);
    f[7] = __uint_as_float(u3 & 0xffff0000u);
}

// ---- probe: decide dtypes from raw bits ----
__global__ void probe_dtypes(const unsigned short* __restrict__ hid_u16,
                             const int* __restrict__ idx_i32) {
    if (threadIdx.x != 0 || blockIdx.x != 0) return;
    // If data is bf16, even-position u16s are real bf16 values of N(0,1):
    // exponent in a sane range. If data is fp32, even positions are the low
    // mantissa bits -> exponent uniformly random (~10% sane).
    int plausible = 0;
    for (int i = 0; i < 64; i += 2) {
        int e = (hid_u16[i] >> 7) & 0xff;
        if (e >= 0x70 && e <= 0x8a) plausible++;
    }
    g_is_fp32 = (plausible < 16) ? 1 : 0;
    // If indices are int64 (values < 64), every odd 32-bit word is 0.
    int oddnz = 0;
    for (int i = 1; i < 64; i += 2)
        if (idx_i32[i] != 0) oddnz++;
    g_idx64 = (oddnz == 0) ? 1 : 0;
}

// ---- transpose up_w [D_OUT][RANK] -> g_up_t [RANK][D_OUT] (fp32) ----
__global__ __launch_bounds__(256) void transpose_up(const void* __restrict__ up_w) {
    const int m = blockIdx.x * 256 + threadIdx.x;
    const int r = m >> 12;            // / D_OUT
    const int o = m & (D_OUT - 1);
    float v;
    if (g_is_fp32) v = ((const float*)up_w)[o * RANK + r];
    else           v = __bfloat162float(((const bf16*)up_w)[o * RANK + r]);
    g_up_t[m] = v;
}

__global__ __launch_bounds__(256) void moe_lora_fused(
    const void* __restrict__ hidden,     // [N, D_IN]
    const void* __restrict__ down_w,     // [RANK, D_IN]
    const void* __restrict__ topk_vals,  // [N, TOPK]
    const void* __restrict__ topk_idx,   // [N, TOPK]
    void* __restrict__ out)              // [N, D_OUT]
{
    const int n = blockIdx.x;
    const int t = threadIdx.x;
    const bool fp32 = (g_is_fp32 != 0);
    const bool idx64 = (g_idx64 != 0);

    __shared__ float red[4][TOPK];
    __shared__ float s_s[TOPK];

    int idx[TOPK];
#pragma unroll
    for (int k = 0; k < TOPK; ++k) {
        int m = n * TOPK + k;
        int v = idx64 ? ((const int*)topk_idx)[2 * m] : ((const int*)topk_idx)[m];
        idx[k] = v & (RANK - 1);   // safety clamp
    }

    // ---- phase 1: s_k = dot(hidden[n], down_w[idx_k]) * val_k ----
    float acc[TOPK];
#pragma unroll
    for (int k = 0; k < TOPK; ++k) acc[k] = 0.0f;

    if (fp32) {
        const float* hrow = (const float*)hidden + (size_t)n * D_IN;
        const float* dw = (const float*)down_w;
#pragma unroll
        for (int i = 0; i < D_IN / (256 * 4); ++i) {   // 4 iterations
            const int off = i * 1024 + t * 4;
            const float4 h = *reinterpret_cast<const float4*>(hrow + off);
#pragma unroll
            for (int k = 0; k < TOPK; ++k) {
                const float4 w = *reinterpret_cast<const float4*>(dw + (size_t)idx[k] * D_IN + off);
                acc[k] = fmaf(h.x, w.x, acc[k]);
                acc[k] = fmaf(h.y, w.y, acc[k]);
                acc[k] = fmaf(h.z, w.z, acc[k]);
                acc[k] = fmaf(h.w, w.w, acc[k]);
            }
        }
    } else {
        const bf16* hrow = (const bf16*)hidden + (size_t)n * D_IN;
        const bf16* dw = (const bf16*)down_w;
#pragma unroll
        for (int i = 0; i < D_IN / (256 * 8); ++i) {   // 2 iterations
            const int off = i * 2048 + t * 8;
            float h[8];
            unpack8(*reinterpret_cast<const uint4*>(hrow + off), h);
#pragma unroll
            for (int k = 0; k < TOPK; ++k) {
                float w[8];
                unpack8(*reinterpret_cast<const uint4*>(dw + (size_t)idx[k] * D_IN + off), w);
#pragma unroll
                for (int j = 0; j < 8; ++j) acc[k] = fmaf(h[j], w[j], acc[k]);
            }
        }
    }

    // wave (64-lane) reduction, then cross-wave via LDS
#pragma unroll
    for (int k = 0; k < TOPK; ++k) {
        float v = acc[k];
        for (int s = 32; s > 0; s >>= 1) v += __shfl_down(v, s, 64);
        acc[k] = v;
    }
    const int wave = t >> 6;
    const int lane = t & 63;
    if (lane == 0) {
#pragma unroll
        for (int k = 0; k < TOPK; ++k) red[wave][k] = acc[k];
    }
    __syncthreads();
    if (t < TOPK) {
        float v = red[0][t] + red[1][t] + red[2][t] + red[3][t];
        float scale = fp32 ? ((const float*)topk_vals)[n * TOPK + t]
                           : __bfloat162float(((const bf16*)topk_vals)[n * TOPK + t]);
        s_s[t] = v * scale;
    }
    __syncthreads();

    float s[TOPK];
#pragma unroll
    for (int k = 0; k < TOPK; ++k) s[k] = s_s[k];

    // ---- phase 2: out[n, o] = sum_k s_k * up_t[idx_k, o] ----
    if (fp32) {
        float* orow = (float*)out + (size_t)n * D_OUT;
#pragma unroll
        for (int i = 0; i < D_OUT / (256 * 4); ++i) {  // 4 iterations
            const int o = i * 1024 + t * 4;
            float4 accO = make_float4(0.f, 0.f, 0.f, 0.f);
#pragma unroll
            for (int k = 0; k < TOPK; ++k) {
                const float4 u = *reinterpret_cast<const float4*>(g_up_t + (size_t)idx[k] * D_OUT + o);
                const float sk = s[k];
                accO.x = fmaf(sk, u.x, accO.x);
                accO.y = fmaf(sk, u.y, accO.y);
                accO.z = fmaf(sk, u.z, accO.z);
                accO.w = fmaf(sk, u.w, accO.w);
            }
            *reinterpret_cast<float4*>(orow + o) = accO;
        }
    } else {
        bf16* orow = (bf16*)out + (size_t)n * D_OUT;
#pragma unroll
        for (int i = 0; i < D_OUT / (256 * 8); ++i) {  // 2 iterations
            const int o = i * 2048 + t * 8;
            float accO[8];
#pragma unroll
            for (int j = 0; j < 8; ++j) accO[j] = 0.0f;
#pragma unroll
            for (int k = 0; k < TOPK; ++k) {
                const float4 u0 = *reinterpret_cast<const float4*>(g_up_t + (size_t)idx[k] * D_OUT + o);
                const float4 u1 = *reinterpret_cast<const float4*>(g_up_t + (size_t)idx[k] * D_OUT + o + 4);
                const float sk = s[k];
                accO[0] = fmaf(sk, u0.x, accO[0]);
                accO[1] = fmaf(sk, u0.y, accO[1]);
                accO[2] = fmaf(sk, u0.z, accO[2]);
                accO[3] = fmaf(sk, u0.w, accO[3]);
                accO[4] = fmaf(sk, u1.x, accO[4]);
                accO[5] = fmaf(sk, u1.y, accO[5]);
                accO[6] = fmaf(sk, u1.z, accO[6]);
                accO[7] = fmaf(sk, u1.w, accO[7]);
            }
            union { uint4 v; bf16 h[8]; } ou;
#pragma unroll
            for (int j = 0; j < 8; ++j) ou.h[j] = __float2bfloat16(accO[j]);
            *reinterpret_cast<uint4*>(orow + o) = ou.v;
        }
    }
}

extern "C" void kernel_launch(void* const* d_in, const int* in_sizes, int n_in,
                              void* d_out, int out_size, void* d_ws, size_t ws_size,
                              hipStream_t stream) {
    const void* hidden = d_in[0];   // [N, D_IN]
    const void* down_w = d_in[1];   // [RANK, D_IN]
    const void* up_w   = d_in[2];   // [D_OUT, RANK]
    const void* vals   = d_in[3];   // [N, TOPK]
    const void* idx    = d_in[4];   // [N, TOPK]

    probe_dtypes<<<1, 64, 0, stream>>>((const unsigned short*)hidden, (const int*)idx);
    transpose_up<<<(RANK * D_OUT) / 256, 256, 0, stream>>>(up_w);
    moe_lora_fused<<<NROWS, 256, 0, stream>>>(hidden, down_w, vals, idx, d_out);
}